// Round 5
// baseline (398.841 us; speedup 1.0000x reference)
//
#include <hip/hip_runtime.h>
#include <math.h>

#define IN_CH 256
#define OUT_CH 64

// ---------------------------------------------------------------------------
// head[n] = -1, cnt[n] = 0
// ---------------------------------------------------------------------------
__global__ void k_init(int* __restrict__ head, int* __restrict__ cnt, int N) {
    int i = blockIdx.x * blockDim.x + threadIdx.x;
    int stride = gridDim.x * blockDim.x;
    for (; i < N; i += stride) { head[i] = -1; cnt[i] = 0; }
}

// ---------------------------------------------------------------------------
// Linked-list adjacency build + in-degree histogram.
// next[e] written coalesced; head/cnt are 400 KB L2-resident atomics.
// ---------------------------------------------------------------------------
__global__ void k_build(const int* __restrict__ dst, int* __restrict__ head,
                        int* __restrict__ next, int* __restrict__ cnt, int E) {
    int i = blockIdx.x * blockDim.x + threadIdx.x;
    int stride = gridDim.x * blockDim.x;
    for (; i < E; i += stride) {
        const int d = dst[i];
        atomicAdd(&cnt[d], 1);
        const int old = atomicExch(&head[d], i);
        next[i] = old;
    }
}

// ---------------------------------------------------------------------------
// g = (x @ W) * dinv[row].  512 thr: 64 rows/block, 8 thr/row x 8 ch.
// W (256x64 f32 = 64KB) staged in LDS; reads are 8-way broadcast b128.
// ---------------------------------------------------------------------------
__global__ __launch_bounds__(512) void k_gemm_scale(
    const float* __restrict__ x, const float* __restrict__ W,
    const int* __restrict__ cnt, float* __restrict__ g, int N)
{
    __shared__ float Wlds[IN_CH * OUT_CH];  // 64 KB
    const int tid = threadIdx.x;
    for (int i = tid * 4; i < IN_CH * OUT_CH; i += 512 * 4) {
        *(float4*)&Wlds[i] = *(const float4*)&W[i];
    }
    __syncthreads();

    const int row = blockIdx.x * 64 + (tid >> 3);
    if (row >= N) return;
    const int cg = (tid & 7) * 8;

    float a[8] = {0.f, 0.f, 0.f, 0.f, 0.f, 0.f, 0.f, 0.f};
    const float* __restrict__ xr = x + (size_t)row * IN_CH;

    for (int k = 0; k < IN_CH; k += 4) {
        const float4 xv = *(const float4*)&xr[k];
        const float xs[4] = {xv.x, xv.y, xv.z, xv.w};
#pragma unroll
        for (int kk = 0; kk < 4; ++kk) {
            const float4 w0 = *(const float4*)&Wlds[(k + kk) * OUT_CH + cg];
            const float4 w1 = *(const float4*)&Wlds[(k + kk) * OUT_CH + cg + 4];
            a[0] += xs[kk] * w0.x; a[1] += xs[kk] * w0.y;
            a[2] += xs[kk] * w0.z; a[3] += xs[kk] * w0.w;
            a[4] += xs[kk] * w1.x; a[5] += xs[kk] * w1.y;
            a[6] += xs[kk] * w1.z; a[7] += xs[kk] * w1.w;
        }
    }

    const float dinv = rsqrtf((float)(cnt[row] + 1));  // +1 self loop
    const size_t o = (size_t)row * OUT_CH + cg;
    *(float4*)&g[o]     = make_float4(a[0]*dinv, a[1]*dinv, a[2]*dinv, a[3]*dinv);
    *(float4*)&g[o + 4] = make_float4(a[4]*dinv, a[5]*dinv, a[6]*dinv, a[7]*dinv);
}

// ---------------------------------------------------------------------------
// One wave per node: chase chain head[i] -> next[...], gathering g[src[e]].
// Chain loads are wave-uniform (broadcast). Then fused bias + log_softmax.
// ---------------------------------------------------------------------------
__global__ void k_aggregate(const int* __restrict__ head, const int* __restrict__ next,
                            const int* __restrict__ srcArr, const int* __restrict__ cnt,
                            const float* __restrict__ g, const float* __restrict__ b,
                            float* __restrict__ out, int N)
{
    const int lane = threadIdx.x & 63;
    int wid = (blockIdx.x * blockDim.x + threadIdx.x) >> 6;
    const int nw = (gridDim.x * blockDim.x) >> 6;
    const float bc = b[lane];

    for (int i = wid; i < N; i += nw) {
        float acc = g[(size_t)i * OUT_CH + lane];  // self loop
        int e = head[i];
        while (e >= 0) {
            const int s  = srcArr[e];
            const int en = next[e];   // issue next-pointer load before the gather
            acc += g[(size_t)s * OUT_CH + lane];
            e = en;
        }

        const float dinv = rsqrtf((float)(cnt[i] + 1));
        const float z = acc * dinv + bc;

        float m = z;
#pragma unroll
        for (int off = 32; off; off >>= 1) m = fmaxf(m, __shfl_xor(m, off));
        float ev = __expf(z - m);
        float s = ev;
#pragma unroll
        for (int off = 32; off; off >>= 1) s += __shfl_xor(s, off);
        out[(size_t)i * OUT_CH + lane] = z - m - __logf(s);
    }
}

// ---------------------------------------------------------------------------
extern "C" void kernel_launch(void* const* d_in, const int* in_sizes, int n_in,
                              void* d_out, int out_size, void* d_ws, size_t ws_size,
                              hipStream_t stream) {
    const float* x  = (const float*)d_in[0];
    const int*   ei = (const int*)d_in[1];
    const float* W  = (const float*)d_in[2];
    const float* b  = (const float*)d_in[3];
    float* out = (float*)d_out;

    const int N = in_sizes[0] / IN_CH;  // 100000
    const int E = in_sizes[1] / 2;      // 1600000
    const int* src = ei;
    const int* dst = ei + E;

    // ws layout: cnt[N] | head[N] | next[E] | g[N*64]   (~33 MB)
    char* p = (char*)d_ws;
    auto alloc = [&](size_t bytes) { char* q = p; p += (bytes + 255) & ~(size_t)255; return q; };
    int*   cnt  = (int*)alloc((size_t)N * 4);
    int*   head = (int*)alloc((size_t)N * 4);
    int*   next = (int*)alloc((size_t)E * 4);
    float* g    = (float*)alloc((size_t)N * OUT_CH * 4);

    k_init      <<<256, 256, 0, stream>>>(head, cnt, N);
    k_build     <<<2048, 256, 0, stream>>>(dst, head, next, cnt, E);
    k_gemm_scale<<<(N + 63) / 64, 512, 0, stream>>>(x, W, cnt, g, N);
    k_aggregate <<<4096, 256, 0, stream>>>(head, next, src, cnt, g, b, out, N);
}

// Round 6
// 372.998 us; speedup vs baseline: 1.0693x; 1.0693x over previous
//
#include <hip/hip_runtime.h>
#include <math.h>

#define IN_CH 256
#define OUT_CH 64
#define SCAN_BS 256
#define SCAN_ITEMS 4
#define SCAN_TILE (SCAN_BS * SCAN_ITEMS)  // 1024

// ---------------------------------------------------------------------------
__global__ void k_init(int* __restrict__ head, int* __restrict__ cnt, int N) {
    int i = blockIdx.x * blockDim.x + threadIdx.x;
    int stride = gridDim.x * blockDim.x;
    for (; i < N; i += stride) { head[i] = -1; cnt[i] = 0; }
}

// ---------------------------------------------------------------------------
// Linked-list adjacency build: next[e] coalesced, head/cnt L2-resident atomics.
// ---------------------------------------------------------------------------
__global__ void k_build(const int* __restrict__ dst, int* __restrict__ head,
                        int* __restrict__ next, int* __restrict__ cnt, int E) {
    int i = blockIdx.x * blockDim.x + threadIdx.x;
    int stride = gridDim.x * blockDim.x;
    for (; i < E; i += stride) {
        const int d = dst[i];
        atomicAdd(&cnt[d], 1);
        const int old = atomicExch(&head[d], i);
        next[i] = old;
    }
}

// ---------------------------------------------------------------------------
// Exclusive scan of cnt -> offs[0..N]
// ---------------------------------------------------------------------------
__global__ void k_scan1(const int* __restrict__ cnt, int* __restrict__ partials, int N) {
    __shared__ int sdata[SCAN_BS];
    const int t = threadIdx.x;
    const int base = blockIdx.x * SCAN_TILE + t * SCAN_ITEMS;
    int s = 0;
#pragma unroll
    for (int j = 0; j < SCAN_ITEMS; ++j) {
        int i = base + j;
        if (i < N) s += cnt[i];
    }
    sdata[t] = s;
    __syncthreads();
    for (int off = SCAN_BS / 2; off > 0; off >>= 1) {
        if (t < off) sdata[t] += sdata[t + off];
        __syncthreads();
    }
    if (t == 0) partials[blockIdx.x] = sdata[0];
}

__global__ void k_scan2(int* __restrict__ partials, int NB) {  // 1 block, 1024 thr
    __shared__ int sdata[1024];
    const int t = threadIdx.x;
    const int orig = (t < NB) ? partials[t] : 0;
    sdata[t] = orig;
    __syncthreads();
    for (int off = 1; off < 1024; off <<= 1) {
        int v = (t >= off) ? sdata[t - off] : 0;
        __syncthreads();
        sdata[t] += v;
        __syncthreads();
    }
    if (t < NB) partials[t] = sdata[t] - orig;  // exclusive
}

__global__ void k_scan3(const int* __restrict__ cnt, const int* __restrict__ partials,
                        int* __restrict__ offs, int N) {
    __shared__ int sdata[SCAN_BS];
    const int t = threadIdx.x;
    const int base = blockIdx.x * SCAN_TILE + t * SCAN_ITEMS;
    int v[SCAN_ITEMS];
    int s = 0;
#pragma unroll
    for (int j = 0; j < SCAN_ITEMS; ++j) {
        int i = base + j;
        v[j] = (i < N) ? cnt[i] : 0;
        s += v[j];
    }
    sdata[t] = s;
    __syncthreads();
    for (int off = 1; off < SCAN_BS; off <<= 1) {
        int u = (t >= off) ? sdata[t - off] : 0;
        __syncthreads();
        sdata[t] += u;
        __syncthreads();
    }
    int run = partials[blockIdx.x] + sdata[t] - s;
#pragma unroll
    for (int j = 0; j < SCAN_ITEMS; ++j) {
        int i = base + j;
        if (i < N) {
            offs[i] = run;
            run += v[j];
            if (i == N - 1) offs[N] = run;
        }
    }
}

// ---------------------------------------------------------------------------
// One THREAD per node: walk chain once, write this node's src list entries
// contiguously (≈64 B/node full-line writes).
// ---------------------------------------------------------------------------
__global__ void k_flatten(const int* __restrict__ head, const int* __restrict__ next,
                          const int* __restrict__ srcArr, const int* __restrict__ offs,
                          int* __restrict__ list, int N) {
    int i = blockIdx.x * blockDim.x + threadIdx.x;
    int stride = gridDim.x * blockDim.x;
    for (; i < N; i += stride) {
        int p = offs[i];
        for (int e = head[i]; e >= 0; e = next[e]) list[p++] = srcArr[e];
    }
}

// ---------------------------------------------------------------------------
// g = (x @ W) * dinv[row].  512 thr: 64 slots x 8 cg; each slot does 4 rows,
// reusing each LDS W read 4x (LDS traffic 6.55 GB -> 1.6 GB).
// ---------------------------------------------------------------------------
__global__ __launch_bounds__(512) void k_gemm_scale(
    const float* __restrict__ x, const float* __restrict__ W,
    const int* __restrict__ cnt, float* __restrict__ g, int N)
{
    __shared__ float Wlds[IN_CH * OUT_CH];  // 64 KB
    const int tid = threadIdx.x;
    for (int i = tid * 4; i < IN_CH * OUT_CH; i += 512 * 4) {
        *(float4*)&Wlds[i] = *(const float4*)&W[i];
    }
    __syncthreads();

    const int slot = tid >> 3;           // 0..63
    const int cg = (tid & 7) * 8;        // channel group start
    const int row0 = blockIdx.x * 256 + slot * 4;

    float a[4][8];
#pragma unroll
    for (int r = 0; r < 4; ++r)
#pragma unroll
        for (int c = 0; c < 8; ++c) a[r][c] = 0.f;

    const int rmax = (row0 + 4 <= N) ? 4 : max(0, N - row0);

    for (int k = 0; k < IN_CH; k += 4) {
        float4 xv[4];
#pragma unroll
        for (int r = 0; r < 4; ++r) {
            const int row = (r < rmax) ? (row0 + r) : (N - 1);  // clamp, discard later
            xv[r] = *(const float4*)&x[(size_t)row * IN_CH + k];
        }
        const float xs[4][4] = {
            {xv[0].x, xv[0].y, xv[0].z, xv[0].w},
            {xv[1].x, xv[1].y, xv[1].z, xv[1].w},
            {xv[2].x, xv[2].y, xv[2].z, xv[2].w},
            {xv[3].x, xv[3].y, xv[3].z, xv[3].w}};
#pragma unroll
        for (int kk = 0; kk < 4; ++kk) {
            const float4 w0 = *(const float4*)&Wlds[(k + kk) * OUT_CH + cg];
            const float4 w1 = *(const float4*)&Wlds[(k + kk) * OUT_CH + cg + 4];
#pragma unroll
            for (int r = 0; r < 4; ++r) {
                a[r][0] += xs[r][kk] * w0.x; a[r][1] += xs[r][kk] * w0.y;
                a[r][2] += xs[r][kk] * w0.z; a[r][3] += xs[r][kk] * w0.w;
                a[r][4] += xs[r][kk] * w1.x; a[r][5] += xs[r][kk] * w1.y;
                a[r][6] += xs[r][kk] * w1.z; a[r][7] += xs[r][kk] * w1.w;
            }
        }
    }

#pragma unroll
    for (int r = 0; r < 4; ++r) {
        if (r < rmax) {
            const int row = row0 + r;
            const float dinv = rsqrtf((float)(cnt[row] + 1));  // +1 self loop
            const size_t o = (size_t)row * OUT_CH + cg;
            *(float4*)&g[o]     = make_float4(a[r][0]*dinv, a[r][1]*dinv, a[r][2]*dinv, a[r][3]*dinv);
            *(float4*)&g[o + 4] = make_float4(a[r][4]*dinv, a[r][5]*dinv, a[r][6]*dinv, a[r][7]*dinv);
        }
    }
}

// ---------------------------------------------------------------------------
// One wave per node: parallel gathers over CSR list + fused bias/log_softmax.
// ---------------------------------------------------------------------------
__global__ void k_aggregate(const int* __restrict__ offs, const int* __restrict__ list,
                            const float* __restrict__ g, const float* __restrict__ b,
                            float* __restrict__ out, int N)
{
    const int lane = threadIdx.x & 63;
    int wid = (blockIdx.x * blockDim.x + threadIdx.x) >> 6;
    const int nw = (gridDim.x * blockDim.x) >> 6;
    const float bc = b[lane];

    for (int i = wid; i < N; i += nw) {
        const int start = offs[i];
        const int end = offs[i + 1];
        float acc = g[(size_t)i * OUT_CH + lane];  // self loop

        for (int e0 = start; e0 < end; e0 += 64) {
            const int n = min(64, end - e0);
            const int idx = (lane < n) ? list[e0 + lane] : 0;
            for (int j = 0; j < n; ++j) {
                const int s = __shfl(idx, j);
                acc += g[(size_t)s * OUT_CH + lane];
            }
        }

        const float dinv = rsqrtf((float)(end - start + 1));
        const float z = acc * dinv + bc;

        float m = z;
#pragma unroll
        for (int off = 32; off; off >>= 1) m = fmaxf(m, __shfl_xor(m, off));
        float ev = __expf(z - m);
        float s = ev;
#pragma unroll
        for (int off = 32; off; off >>= 1) s += __shfl_xor(s, off);
        out[(size_t)i * OUT_CH + lane] = z - m - __logf(s);
    }
}

// ---------------------------------------------------------------------------
extern "C" void kernel_launch(void* const* d_in, const int* in_sizes, int n_in,
                              void* d_out, int out_size, void* d_ws, size_t ws_size,
                              hipStream_t stream) {
    const float* x  = (const float*)d_in[0];
    const int*   ei = (const int*)d_in[1];
    const float* W  = (const float*)d_in[2];
    const float* b  = (const float*)d_in[3];
    float* out = (float*)d_out;

    const int N = in_sizes[0] / IN_CH;  // 100000
    const int E = in_sizes[1] / 2;      // 1600000
    const int* src = ei;
    const int* dst = ei + E;

    const int NB = (N + SCAN_TILE - 1) / SCAN_TILE;  // 98

    // ws: cnt[N] | head[N] | next[E] | offs[N+1] | partials[1024] | list[E] | g[N*64]
    char* p = (char*)d_ws;
    auto alloc = [&](size_t bytes) { char* q = p; p += (bytes + 255) & ~(size_t)255; return q; };
    int*   cnt      = (int*)alloc((size_t)N * 4);
    int*   head     = (int*)alloc((size_t)N * 4);
    int*   next     = (int*)alloc((size_t)E * 4);
    int*   offs     = (int*)alloc((size_t)(N + 1) * 4);
    int*   partials = (int*)alloc(1024 * 4);
    int*   list     = (int*)alloc((size_t)E * 4);
    float* g        = (float*)alloc((size_t)N * OUT_CH * 4);

    k_init      <<<256, 256, 0, stream>>>(head, cnt, N);
    k_build     <<<2048, 256, 0, stream>>>(dst, head, next, cnt, E);
    k_scan1     <<<NB, SCAN_BS, 0, stream>>>(cnt, partials, N);
    k_scan2     <<<1, 1024, 0, stream>>>(partials, NB);
    k_scan3     <<<NB, SCAN_BS, 0, stream>>>(cnt, partials, offs, N);
    k_flatten   <<<512, 256, 0, stream>>>(head, next, src, offs, list, N);
    k_gemm_scale<<<(N + 255) / 256, 512, 0, stream>>>(x, W, cnt, g, N);
    k_aggregate <<<4096, 256, 0, stream>>>(offs, list, g, b, out, N);
}